// Round 15
// baseline (177.886 us; speedup 1.0000x reference)
//
#include <hip/hip_runtime.h>
#include <cstdint>

constexpr int BG = 256;        // graphs
constexpr int MAXN = 2000;
constexpr int NPARTS = 10;

// ---------------- utility: fast zero (grid-stride int4) ----------------

__global__ void k_zeroi(int4* __restrict__ p, size_t n4) {
  size_t i = (size_t)blockIdx.x * blockDim.x + threadIdx.x;
  size_t stride = (size_t)gridDim.x * blockDim.x;
  for (; i < n4; i += stride) p[i] = make_int4(0, 0, 0, 0);
}

// zero only padding positions of dense: pos in [cnt, MAXN) per graph/channel
__global__ void k_zero_pad(float* __restrict__ dense, const int* __restrict__ cum) {
  int b = blockIdx.x;
  int cnt = cum[b + 1] - cum[b];
  for (int pos = cnt + threadIdx.x; pos < MAXN; pos += blockDim.x) {
    #pragma unroll
    for (int c = 0; c < 8; c++)
      dense[((size_t)(b * 8 + c)) * MAXN + pos] = 0.f;
  }
}

// ---------------- batch boundaries (no atomics; batch is sorted) ----------------

__global__ void k_bounds(const int* __restrict__ batch, int* __restrict__ cum, int N) {
  int i = blockIdx.x * blockDim.x + threadIdx.x;
  if (i >= N) return;
  int b = batch[i];
  if (i == 0) cum[b] = 0;
  else if (batch[i - 1] != b) cum[b] = i;
  if (i == N - 1) cum[BG] = N;
}

// ---------------- CSR build ----------------

__global__ void k_deg_int(const int* __restrict__ dst, int* __restrict__ deg, int E) {
  int e = blockIdx.x * blockDim.x + threadIdx.x;
  if (e < E) atomicAdd(&deg[dst[e]], 1);
}

__global__ void k_blocksum(const int* __restrict__ deg, int* __restrict__ bsum, int N) {
  __shared__ int sd[256];
  int i = blockIdx.x * 256 + threadIdx.x;
  sd[threadIdx.x] = (i < N) ? deg[i] : 0;
  __syncthreads();
  for (int s = 128; s > 0; s >>= 1) {
    if (threadIdx.x < s) sd[threadIdx.x] += sd[threadIdx.x + s];
    __syncthreads();
  }
  if (threadIdx.x == 0) bsum[blockIdx.x] = sd[0];
}

// parallel exclusive scan of bsum[0..nb) with one 256-thread block
__global__ __launch_bounds__(256)
void k_scanb(int* __restrict__ bsum, int nb) {
  __shared__ int part[256];
  int tid = threadIdx.x;
  int per = (nb + 255) / 256;
  int beg = tid * per;
  int end = beg + per; if (end > nb) end = nb;
  int s = 0;
  for (int i = beg; i < end; i++) s += bsum[i];
  part[tid] = s;
  __syncthreads();
  for (int off = 1; off < 256; off <<= 1) {
    int t = (tid >= off) ? part[tid - off] : 0;
    __syncthreads();
    part[tid] += t;
    __syncthreads();
  }
  int run = part[tid] - s;   // exclusive prefix of this chunk
  for (int i = beg; i < end; i++) { int v = bsum[i]; bsum[i] = run; run += v; }
}

// rowptr + dinv fused (deg already loaded here)
__global__ void k_rowptr(const int* __restrict__ deg, const int* __restrict__ bsum,
                         int* __restrict__ rowptr, float* __restrict__ dinvf, int N) {
  __shared__ int sc[256];
  int tid = threadIdx.x;
  int i = blockIdx.x * 256 + tid;
  int v = (i < N) ? deg[i] : 0;
  sc[tid] = v;
  __syncthreads();
  for (int off = 1; off < 256; off <<= 1) {
    int t = (tid >= off) ? sc[tid - off] : 0;
    __syncthreads();
    sc[tid] += t;
    __syncthreads();
  }
  if (i < N) {
    rowptr[i] = bsum[blockIdx.x] + sc[tid] - v;   // exclusive
    dinvf[i] = rsqrtf((float)v + 1.0f);           // +1 self-loop
  }
  if (i == N - 1) rowptr[N] = bsum[blockIdx.x] + sc[tid];  // total = E
}

__global__ void k_fill(const int* __restrict__ src, const int* __restrict__ dst,
                       const int* __restrict__ rowptr, int* __restrict__ cursor,
                       int* __restrict__ adj, int E) {
  int e = blockIdx.x * blockDim.x + threadIdx.x;
  if (e >= E) return;
  int d = dst[e];
  int p = atomicAdd(&cursor[d], 1);
  adj[rowptr[d] + p] = src[e];
}

// ---------------- GCN dense parts ----------------

__global__ void k_xw1(const float* __restrict__ x, const float* __restrict__ W1,
                      const float* __restrict__ dinv, float* __restrict__ A, int N) {
  int i = blockIdx.x * blockDim.x + threadIdx.x;
  if (i >= N) return;
  float4 xi = ((const float4*)x)[i];
  float di = dinv[i];
  #pragma unroll
  for (int c = 0; c < 8; c++) {
    float s = xi.x * W1[c] + xi.y * W1[8 + c] + xi.z * W1[16 + c] + xi.w * W1[24 + c];
    A[(size_t)i * 8 + c] = s * di;
  }
}

__global__ void k_gather_l1(const float* __restrict__ A, const int* __restrict__ rowptr,
                            const int* __restrict__ adj, const float* __restrict__ dinv,
                            const float* __restrict__ b1, const float* __restrict__ W2,
                            float* __restrict__ A2, int N) {
  int i = blockIdx.x * blockDim.x + threadIdx.x;
  if (i >= N) return;
  const float4* Ai = (const float4*)(A + (size_t)i * 8);
  float4 s0 = Ai[0], s1 = Ai[1];
  int beg = rowptr[i], end = rowptr[i + 1];
  for (int j = beg; j < end; j++) {
    const float4* As = (const float4*)(A + (size_t)adj[j] * 8);
    float4 a0 = As[0], a1 = As[1];
    s0.x += a0.x; s0.y += a0.y; s0.z += a0.z; s0.w += a0.w;
    s1.x += a1.x; s1.y += a1.y; s1.z += a1.z; s1.w += a1.w;
  }
  float di = dinv[i];
  float h[8];
  h[0] = fmaxf(s0.x * di + b1[0], 0.f); h[1] = fmaxf(s0.y * di + b1[1], 0.f);
  h[2] = fmaxf(s0.z * di + b1[2], 0.f); h[3] = fmaxf(s0.w * di + b1[3], 0.f);
  h[4] = fmaxf(s1.x * di + b1[4], 0.f); h[5] = fmaxf(s1.y * di + b1[5], 0.f);
  h[6] = fmaxf(s1.z * di + b1[6], 0.f); h[7] = fmaxf(s1.w * di + b1[7], 0.f);
  #pragma unroll
  for (int c = 0; c < 8; c++) {
    float a = 0.f;
    #pragma unroll
    for (int k = 0; k < 8; k++) a += h[k] * W2[k * 8 + c];
    A2[(size_t)i * 8 + c] = a * di;
  }
}

__global__ void k_gather_l2(const float* __restrict__ A2, const int* __restrict__ rowptr,
                            const int* __restrict__ adj, const float* __restrict__ dinv,
                            const float* __restrict__ b2, const int* __restrict__ batch,
                            const int* __restrict__ cum, float* __restrict__ dense, int N) {
  int i = blockIdx.x * blockDim.x + threadIdx.x;
  if (i >= N) return;
  const float4* Ai = (const float4*)(A2 + (size_t)i * 8);
  float4 s0 = Ai[0], s1 = Ai[1];
  int beg = rowptr[i], end = rowptr[i + 1];
  for (int j = beg; j < end; j++) {
    const float4* As = (const float4*)(A2 + (size_t)adj[j] * 8);
    float4 a0 = As[0], a1 = As[1];
    s0.x += a0.x; s0.y += a0.y; s0.z += a0.z; s0.w += a0.w;
    s1.x += a1.x; s1.y += a1.y; s1.z += a1.z; s1.w += a1.w;
  }
  float di = dinv[i];
  float h[8];
  h[0] = fmaxf(s0.x * di + b2[0], 0.f); h[1] = fmaxf(s0.y * di + b2[1], 0.f);
  h[2] = fmaxf(s0.z * di + b2[2], 0.f); h[3] = fmaxf(s0.w * di + b2[3], 0.f);
  h[4] = fmaxf(s1.x * di + b2[4], 0.f); h[5] = fmaxf(s1.y * di + b2[5], 0.f);
  h[6] = fmaxf(s1.z * di + b2[6], 0.f); h[7] = fmaxf(s1.w * di + b2[7], 0.f);
  int b = batch[i];
  int pos = i - cum[b];
  #pragma unroll
  for (int c = 0; c < 8; c++)
    dense[((size_t)(b * 8 + c)) * MAXN + pos] = h[c];
}

// ---------------- conv1d(k=5,'same') + relu + mean-pool2 — NP=2, TLP latency hiding ----------------
// grid (BG, COG, LT) = 2048 blocks (8/CU = 32 waves/CU). __launch_bounds__(256,8) caps
// VGPR at 64 (acc 16 + 3 float4 + addr fits). Weights via wave-uniform scalar loads.
// Lane -> 2 pooled positions (4 conv cols, 8 input cols). 3 aligned float4 loads per ci,
// bases clamped to [0, L-4]; right-overrun feeds only unstored outputs; left edge zeroes.
template<int CIN, int COUT, int L, int COG, int LT>
__global__ __launch_bounds__(256, 8)
void k_conv(const float* __restrict__ in, const float* __restrict__ w,
            const float* __restrict__ bias, float* __restrict__ out) {
  constexpr int LOUT = L / 2;
  constexpr int COPB = COUT / COG;      // 16 out-channels per block
  constexpr int NCO = COPB / 4;         // 4 per wave
  constexpr int TP = 128;               // pooled positions per tile (64 lanes x 2)

  const int lane = threadIdx.x & 63;
  const int wv = threadIdx.x >> 6;
  const int co0 = __builtin_amdgcn_readfirstlane(blockIdx.y * COPB + wv * NCO);
  const int p0 = blockIdx.z * TP + lane * 2;   // first pooled pos (even)
  const int a0 = 2 * p0 - 4;                   // aligned load base (mult of 4)
  const bool lz = (p0 == 0);
  const float* __restrict__ inb = in + (size_t)blockIdx.x * CIN * L;

  int bas[3];
  #pragma unroll
  for (int m = 0; m < 3; m++) {
    int rb = a0 + 4 * m;
    rb = rb < 0 ? 0 : rb;
    bas[m] = rb > (L - 4) ? (L - 4) : rb;
  }

  float acc[NCO][4];
  #pragma unroll
  for (int g = 0; g < NCO; g++)
    #pragma unroll
    for (int q = 0; q < 4; q++) acc[g][q] = 0.f;

  for (int ci = 0; ci < CIN; ci++) {
    const float* s = inb + (size_t)ci * L;
    float4 q0 = *(const float4*)(s + bas[0]);
    float4 q1 = *(const float4*)(s + bas[1]);
    float4 q2 = *(const float4*)(s + bas[2]);
    // r[j] = col a0+j (modulo clamping); f[j] = col i0+j = r[j+2], j=0..7
    float r[12];
    r[0] = q0.x; r[1] = q0.y; r[2] = q0.z; r[3] = q0.w;
    r[4] = q1.x; r[5] = q1.y; r[6] = q1.z; r[7] = q1.w;
    r[8] = q2.x; r[9] = q2.y; r[10] = q2.z; r[11] = q2.w;
    if (lz) { r[2] = 0.f; r[3] = 0.f; }   // cols -2,-1
    #pragma unroll
    for (int g = 0; g < NCO; g++) {
      const float* wg = w + ((size_t)(co0 + g) * CIN + ci) * 5;  // wave-uniform -> s_load
      float v0 = wg[0], v1 = wg[1], v2 = wg[2], v3 = wg[3], v4 = wg[4];
      #pragma unroll
      for (int q = 0; q < 4; q++)
        acc[g][q] += v0 * r[q + 2] + v1 * r[q + 3] + v2 * r[q + 4]
                   + v3 * r[q + 5] + v4 * r[q + 6];
    }
  }

  #pragma unroll
  for (int g = 0; g < NCO; g++) {
    int co = co0 + g;
    float bv = bias[co];
    float t0, t1;
    {
      float y0 = fmaxf(acc[g][0] + bv, 0.f);
      float y1 = fmaxf(acc[g][1] + bv, 0.f);
      t0 = 0.5f * (y0 + y1);
      float y2 = fmaxf(acc[g][2] + bv, 0.f);
      float y3 = fmaxf(acc[g][3] + bv, 0.f);
      t1 = 0.5f * (y2 + y3);
    }
    float* op = out + (size_t)(blockIdx.x * COUT + co) * LOUT + p0;
    if (p0 + 1 < LOUT) {
      *(float2*)op = make_float2(t0, t1);
    } else if (p0 < LOUT) {
      op[0] = t0;
    }
  }
}

// ---------------- fused head: segment means + MLP (one block per graph) ----------------
__global__ __launch_bounds__(256)
void k_head(const float* __restrict__ xp, const int* __restrict__ cum,
            const float* __restrict__ fw1, const float* __restrict__ fb1,
            const float* __restrict__ fw2, const float* __restrict__ fb2,
            float* __restrict__ out) {
  constexpr int LC = MAXN / 8;   // 250
  __shared__ float seg[640];
  __shared__ float hid[100];
  int b = blockIdx.x;
  int valid = (cum[b + 1] - cum[b]) >> 3;
  int base = valid / NPARTS, rem = valid % NPARTS;
  for (int idx = threadIdx.x; idx < 64 * NPARTS; idx += 256) {
    int c = idx / NPARTS, j = idx % NPARTS;
    int size = base + (j < rem ? 1 : 0);
    int start = j * base + (j < rem ? j : rem);
    const float* p = xp + ((size_t)b * 64 + c) * LC + start;
    float s = 0.f;
    for (int t = 0; t < size; t++) s += p[t];
    seg[idx] = s / (float)size;   // seg[c*10+j]
  }
  __syncthreads();
  int t = threadIdx.x;
  if (t < 100) {
    float acc = fb1[t];
    for (int k = 0; k < 640; k++) acc += seg[k] * fw1[(size_t)k * 100 + t];
    hid[t] = fmaxf(acc, 0.f);
  }
  __syncthreads();
  if (t < 2) {
    float acc = fb2[t];
    for (int k = 0; k < 100; k++) acc += hid[k] * fw2[k * 2 + t];
    out[b * 2 + t] = acc;
  }
}

extern "C" void kernel_launch(void* const* d_in, const int* in_sizes, int n_in,
                              void* d_out, int out_size, void* d_ws, size_t ws_size,
                              hipStream_t stream) {
  const float* x   = (const float*)d_in[0];
  const int*   ei  = (const int*)d_in[1];
  const int* batch = (const int*)d_in[2];
  const float* W1  = (const float*)d_in[3];
  const float* b1  = (const float*)d_in[4];
  const float* W2  = (const float*)d_in[5];
  const float* b2  = (const float*)d_in[6];
  const float* cw1 = (const float*)d_in[7];
  const float* cb1 = (const float*)d_in[8];
  const float* cw2 = (const float*)d_in[9];
  const float* cb2 = (const float*)d_in[10];
  const float* cw3 = (const float*)d_in[11];
  const float* cb3 = (const float*)d_in[12];
  const float* fw1 = (const float*)d_in[13];
  const float* fb1 = (const float*)d_in[14];
  const float* fw2 = (const float*)d_in[15];
  const float* fb2 = (const float*)d_in[16];
  float* outp = (float*)d_out;

  int N = in_sizes[0] / 4;
  int E = in_sizes[1] / 2;
  size_t N8 = (size_t)N * 8;
  int nbN = (N + 255) / 256, nbE = (E + 255) / 256;

  float* wsf  = (float*)d_ws;
  float* A    = wsf;
  float* Bb   = A + N8;              // A2 for layer 2
  int* degI   = (int*)(Bb + N8);     // N ints
  int* cursor = degI + N;            // N ints (adjacent -> one zero pass)
  float* dinv = (float*)(cursor + N);// N floats
  int* cum    = (int*)(dinv + N);    // BG+1 ints
  float* D0   = (float*)(((uintptr_t)(cum + BG + 1) + 255) & ~(uintptr_t)255);
  float* D1   = D0 + (size_t)BG * 8 * MAXN;

  // CSR temporaries aliased into D1 (D1 first written by conv1, after fill/gathers)
  int* rowptr = (int*)D1;            // N+1
  int* adj    = rowptr + (N + 1);    // E
  int* bsum   = adj + E;             // nbN

  // --- boundaries (no atomics) ---
  k_bounds<<<nbN, 256, 0, stream>>>(batch, cum, N);

  // --- CSR build ---
  k_zeroi<<<1024, 256, 0, stream>>>((int4*)degI, (size_t)(2 * N) / 4);  // degI + cursor
  k_deg_int<<<nbE, 256, 0, stream>>>(ei + E, degI, E);
  k_blocksum<<<nbN, 256, 0, stream>>>(degI, bsum, N);
  k_scanb<<<1, 256, 0, stream>>>(bsum, nbN);
  k_rowptr<<<nbN, 256, 0, stream>>>(degI, bsum, rowptr, dinv, N);
  k_fill<<<nbE, 256, 0, stream>>>(ei, ei + E, rowptr, cursor, adj, E);

  // --- GCN (gather, no atomics) ---
  k_xw1<<<nbN, 256, 0, stream>>>(x, W1, dinv, A, N);
  k_gather_l1<<<nbN, 256, 0, stream>>>(A, rowptr, adj, dinv, b1, W2, Bb, N);
  k_zero_pad<<<BG, 256, 0, stream>>>(D0, cum);   // zero only pos >= cnt
  k_gather_l2<<<nbN, 256, 0, stream>>>(Bb, rowptr, adj, dinv, b2, batch, cum, D0, N);

  // --- convs: NP=2, scalar weights, 2048 blocks each (8/CU, 100% occupancy) ---
  k_conv<8, 16, 2000, 1, 8><<<dim3(BG, 1, 8), 256, 0, stream>>>(D0, cw1, cb1, D1);
  k_conv<16, 32, 1000, 2, 4><<<dim3(BG, 2, 4), 256, 0, stream>>>(D1, cw2, cb2, D0);
  k_conv<32, 64, 500, 4, 2><<<dim3(BG, 4, 2), 256, 0, stream>>>(D0, cw3, cb3, D1);

  // --- fused segment means + MLP ---
  k_head<<<BG, 256, 0, stream>>>(D1, cum, fw1, fb1, fw2, fb2, outp);
}